// Round 13
// baseline (603.154 us; speedup 1.0000x reference)
//
#include <hip/hip_runtime.h>
#include <hip/hip_bf16.h>

#define N_NODES 100000
#define N_EDGES 3200000
#define N_GRAPHS 512
#define IN_DIM 29
#define HID 128
#define LAT 256
#define NB 391     // ceil(N_NODES/256) dst-buckets
#define CAP 9216   // per-bucket packed capacity (mean 8184, sigma~90 -> +11 sigma)

typedef unsigned int uint;
typedef unsigned short ushort;
typedef float v4f __attribute__((ext_vector_type(4)));
typedef short v8s __attribute__((ext_vector_type(8)));

// round-to-nearest-even fp32 -> bf16 (finite inputs)
__device__ __forceinline__ ushort f2bf(float f) {
    uint u = __float_as_uint(f);
    return (ushort)((u + 0x7FFFu + ((u >> 16) & 1u)) >> 16);
}
__device__ __forceinline__ float bf2f(ushort h) { return __uint_as_float(((uint)h) << 16); }
__device__ __forceinline__ float bf_lo(uint p) { return __uint_as_float(p << 16); }
__device__ __forceinline__ float bf_hi(uint p) { return __uint_as_float(p & 0xFFFF0000u); }
__device__ __forceinline__ uint pack2(float a, float b) {
    return (uint)f2bf(a) | ((uint)f2bf(b) << 16);
}

__device__ __forceinline__ void bfadd(float* a, uint4 q) {
    a[0] += bf_lo(q.x); a[1] += bf_hi(q.x);
    a[2] += bf_lo(q.y); a[3] += bf_hi(q.y);
    a[4] += bf_lo(q.z); a[5] += bf_hi(q.z);
    a[6] += bf_lo(q.w); a[7] += bf_hi(q.w);
}

// ---------------- preprocessing ----------------

// Single-pass binning with WAVE-PRIVATE histograms (4 copies) to cut LDS-atomic
// serialization ~4x. Each wave counts into hist[w], block combine reserves one
// global region per bucket, per-wave disjoint bases derived by prefix over waves.
// pack (dst&255)<<17 | src. bktCnt[b] counts edges per bucket.
__global__ __launch_bounds__(256, 4) void k_binA(const int* __restrict__ src, const int* __restrict__ dst,
                                                 int* __restrict__ bktCnt, int* __restrict__ packed, int e) {
    __shared__ int hist[4][NB];
    __shared__ int base[4][NB];
    int t = threadIdx.x;
    int w = t >> 6;
    for (int i = t; i < 4 * NB; i += 256) ((int*)hist)[i] = 0;
    __syncthreads();
    int d[16], s[16];
    const int blockStart = blockIdx.x * 4096;
    #pragma unroll
    for (int k = 0; k < 16; ++k) {
        int idx = blockStart + k * 256 + t;
        if (idx < e) {
            d[k] = dst[idx];
            s[k] = src[idx];
            atomicAdd(&hist[w][d[k] >> 8], 1);
        } else d[k] = -1;
    }
    __syncthreads();
    for (int i = t; i < NB; i += 256) {
        int h0 = hist[0][i], h1 = hist[1][i], h2 = hist[2][i], h3 = hist[3][i];
        int tot = h0 + h1 + h2 + h3;
        int blockBase = tot ? atomicAdd(&bktCnt[i], tot) : 0;
        base[0][i] = blockBase;
        base[1][i] = blockBase + h0;
        base[2][i] = blockBase + h0 + h1;
        base[3][i] = blockBase + h0 + h1 + h2;
    }
    __syncthreads();
    #pragma unroll
    for (int k = 0; k < 16; ++k) {
        if (d[k] >= 0) {
            int b = d[k] >> 8;
            int pos = atomicAdd(&base[w][b], 1);
            if (pos < CAP) packed[b * CAP + pos] = ((d[k] & 255) << 17) | s[k];
        }
    }
}

// single block: exclusive scan of bktCnt -> colStart[NB+1] (dense col layout)
__global__ __launch_bounds__(512) void k_bscan(const int* __restrict__ bktCnt, int* __restrict__ colStart) {
    __shared__ int sh[512];
    int t = threadIdx.x;
    int v = (t < NB) ? bktCnt[t] : 0;
    if (v > CAP) v = CAP;
    sh[t] = v;
    __syncthreads();
    for (int off = 1; off < 512; off <<= 1) {
        int x = (t >= off) ? sh[t - off] : 0;
        __syncthreads();
        sh[t] += x;
        __syncthreads();
    }
    int excl = sh[t] - v;
    if (t <= NB) colStart[t] = excl;
}

// Phase B: per bucket — wave-private per-node degree counts (4 copies), scan of
// combined degrees -> rp & dis (coalesced), then per-wave disjoint scatter of col
// to final dense CSR positions (L2-resident region). Same per-thread striding in
// count and scatter loops guarantees wave w scatters exactly what it counted.
__global__ __launch_bounds__(256, 4) void k_binB(const int* __restrict__ bktCnt, const int* __restrict__ colStart,
                                                 const int* __restrict__ packed, int* __restrict__ col,
                                                 int* __restrict__ rp, float* __restrict__ dis, int n) {
    const int b = blockIdx.x;
    int cntB = bktCnt[b];
    if (cntB > CAP) cntB = CAP;
    const int segS = b * CAP;
    const int colBase = colStart[b];
    __shared__ int cnt[4][256];
    __shared__ int sh[256];
    __shared__ int cur[4][256];
    int t = threadIdx.x;
    int w = t >> 6;
    cnt[0][t] = 0; cnt[1][t] = 0; cnt[2][t] = 0; cnt[3][t] = 0;
    __syncthreads();
    for (int j = segS + t; j < segS + cntB; j += 256) atomicAdd(&cnt[w][packed[j] >> 17], 1);
    __syncthreads();
    int c0 = cnt[0][t], c1 = cnt[1][t], c2 = cnt[2][t], c3 = cnt[3][t];
    int v = c0 + c1 + c2 + c3;
    sh[t] = v;
    __syncthreads();
    for (int off = 1; off < 256; off <<= 1) {
        int x = (t >= off) ? sh[t - off] : 0;
        __syncthreads();
        sh[t] += x;
        __syncthreads();
    }
    int excl = sh[t] - v;
    int node = (b << 8) + t;
    int start = colBase + excl;
    cur[0][t] = start;
    cur[1][t] = start + c0;
    cur[2][t] = start + c0 + c1;
    cur[3][t] = start + c0 + c1 + c2;
    if (node <= n) rp[node] = start;      // node==n (last bucket) -> rp[n] = E
    if (node < n) dis[node] = rsqrtf((float)v + 1.0f);
    __syncthreads();
    for (int j = segS + t; j < segS + cntB; j += 256) {
        int pk = packed[j];
        int dl = pk >> 17;
        int pos = atomicAdd(&cur[w][dl], 1);
        col[pos] = pk & 0x1FFFF;
    }
}

// ---------------- W pack (all 3 layers) + zero bktCnt (runs first) ----------------
// layout index = ((kstep*8 + ntile)*64 + lane)*8 + j
// element = W[kstep*32 + (lane>>4)*8 + j][ntile*16 + (lane&15)]

__device__ __forceinline__ void pack_one(const float* W, ushort* hi, ushort* lo, int Ksrc, int idx) {
    int j = idx & 7;
    int lane = (idx >> 3) & 63;
    int nt = (idx >> 9) & 7;
    int ks = idx >> 12;
    int k = ks * 32 + (lane >> 4) * 8 + j;
    int n = nt * 16 + (lane & 15);
    float v = (k < Ksrc) ? W[k * 128 + n] : 0.f;
    ushort h = f2bf(v);
    ushort l = f2bf(v - bf2f(h));
    hi[idx] = h;
    lo[idx] = l;
}

__global__ __launch_bounds__(256) void k_pack_all(const float* __restrict__ W1, const float* __restrict__ W2,
                                                  const float* __restrict__ W3,
                                                  ushort* w1h, ushort* w1l, ushort* w2h, ushort* w2l,
                                                  ushort* w3h, ushort* w3l, int* __restrict__ bktCnt) {
    int idx = blockIdx.x * 256 + threadIdx.x;
    if (idx < NB) bktCnt[idx] = 0;        // fold the zeroing launch in here
    if (idx < 4096) {
        pack_one(W1, w1h, w1l, IN_DIM, idx);
    } else if (idx < 4096 + 16384) {
        pack_one(W2, w2h, w2l, HID, idx - 4096);
    } else if (idx < 4096 + 32768) {
        pack_one(W3, w3h, w3l, HID, idx - 4096 - 16384);
    }
}

// ---------------- MFMA GEMM (layer 1): hws = dis * (x_f32 @ W) ----------------
// Split precision: acc = Ahi@Whi + Ahi@Wlo + Alo@Whi.

__global__ __launch_bounds__(256, 6) void k_gemm_mfma_f32(const float* __restrict__ in,
                                                          const ushort* __restrict__ Whi,
                                                          const ushort* __restrict__ Wlo,
                                                          const float* __restrict__ dis,
                                                          ushort* __restrict__ out, int n) {
    const int wave = threadIdx.x >> 6;
    const int lane = threadIdx.x & 63;
    const int m0 = (blockIdx.x * 4 + wave) * 16;
    if (m0 >= n) return;
    int row = m0 + (lane & 15);
    if (row >= n) row = n - 1;
    const int kh = (lane >> 4) * 8;
    const float* rptr = in + (size_t)row * IN_DIM + kh;

    v4f acc[8];
    #pragma unroll
    for (int t = 0; t < 8; ++t) acc[t] = (v4f){0.f, 0.f, 0.f, 0.f};

    float a[8];
    #pragma unroll
    for (int j = 0; j < 8; ++j) a[j] = (kh + j < IN_DIM) ? rptr[j] : 0.f;
    v8s ahi, alo;
    #pragma unroll
    for (int j = 0; j < 8; ++j) {
        ushort h = f2bf(a[j]);
        ushort l = f2bf(a[j] - bf2f(h));
        ahi[j] = (short)h;
        alo[j] = (short)l;
    }
    const ushort* bh = Whi + (size_t)lane * 8;
    const ushort* bl = Wlo + (size_t)lane * 8;
    #pragma unroll
    for (int nt = 0; nt < 8; ++nt) {
        v8s bhi = *(const v8s*)(bh + nt * 512);
        v8s blo = *(const v8s*)(bl + nt * 512);
        acc[nt] = __builtin_amdgcn_mfma_f32_16x16x32_bf16(ahi, bhi, acc[nt], 0, 0, 0);
        acc[nt] = __builtin_amdgcn_mfma_f32_16x16x32_bf16(ahi, blo, acc[nt], 0, 0, 0);
        acc[nt] = __builtin_amdgcn_mfma_f32_16x16x32_bf16(alo, bhi, acc[nt], 0, 0, 0);
    }

    const int orow0 = m0 + (lane >> 4) * 4;
    const int col0 = lane & 15;
    #pragma unroll
    for (int r = 0; r < 4; ++r) {
        int orow = orow0 + r;
        if (orow < n) {
            float dv = dis[orow];
            #pragma unroll
            for (int nt = 0; nt < 8; ++nt)
                out[(size_t)orow * 128 + nt * 16 + col0] = f2bf(acc[nt][r] * dv);
        }
    }
}

// ---------------- MFMA GEMM (layers 2,3): hws = dis * (h_bf16 @ W) ----------------
// A exact bf16 -> 2 MFMAs: A@Whi + A@Wlo.

__global__ __launch_bounds__(256, 6) void k_gemm_mfma_bf(const ushort* __restrict__ in,
                                                         const ushort* __restrict__ Whi,
                                                         const ushort* __restrict__ Wlo,
                                                         const float* __restrict__ dis,
                                                         ushort* __restrict__ out, int n) {
    const int wave = threadIdx.x >> 6;
    const int lane = threadIdx.x & 63;
    const int m0 = (blockIdx.x * 4 + wave) * 16;
    if (m0 >= n) return;
    int row = m0 + (lane & 15);
    if (row >= n) row = n - 1;
    const int kh = (lane >> 4) * 8;
    const ushort* rptr = in + (size_t)row * 128 + kh;

    v4f acc[8];
    #pragma unroll
    for (int t = 0; t < 8; ++t) acc[t] = (v4f){0.f, 0.f, 0.f, 0.f};

    #pragma unroll
    for (int ks = 0; ks < 4; ++ks) {
        v8s a = *(const v8s*)(rptr + ks * 32);
        const ushort* bh = Whi + (size_t)(ks * 8) * 512 + (size_t)lane * 8;
        const ushort* bl = Wlo + (size_t)(ks * 8) * 512 + (size_t)lane * 8;
        #pragma unroll
        for (int nt = 0; nt < 8; ++nt) {
            v8s bhi = *(const v8s*)(bh + nt * 512);
            v8s blo = *(const v8s*)(bl + nt * 512);
            acc[nt] = __builtin_amdgcn_mfma_f32_16x16x32_bf16(a, bhi, acc[nt], 0, 0, 0);
            acc[nt] = __builtin_amdgcn_mfma_f32_16x16x32_bf16(a, blo, acc[nt], 0, 0, 0);
        }
    }

    const int orow0 = m0 + (lane >> 4) * 4;
    const int col0 = lane & 15;
    #pragma unroll
    for (int r = 0; r < 4; ++r) {
        int orow = orow0 + r;
        if (orow < n) {
            float dv = dis[orow];
            #pragma unroll
            for (int nt = 0; nt < 8; ++nt)
                out[(size_t)orow * 128 + nt * 16 + col0] = f2bf(acc[nt][r] * dv);
        }
    }
}

// ---------------- aggregation (R9-exact): 16 lanes/node, 8 ch/lane, 4 edges in flight ----------------
// out[i][:] = bf16( relu( dis[i] * ( sum_j hws[col[j]][:] + hws[i][:] ) + b[:] ) )

__global__ __launch_bounds__(256, 8) void k_agg(const ushort* __restrict__ hws, const int* __restrict__ rp,
                                                const int* __restrict__ col, const float* __restrict__ dis,
                                                const float* __restrict__ bias, ushort* __restrict__ out, int n) {
    int node = (int)((blockIdx.x * 256 + threadIdx.x) >> 4);
    if (node >= n) return;
    int c8 = (threadIdx.x & 15) << 3;
    int s = rp[node], e = rp[node + 1];
    float A[8] = {0.f, 0.f, 0.f, 0.f, 0.f, 0.f, 0.f, 0.f};
    float B[8] = {0.f, 0.f, 0.f, 0.f, 0.f, 0.f, 0.f, 0.f};
    int j = s;
    for (; j + 3 < e; j += 4) {
        int c0 = col[j], c1 = col[j + 1], c2 = col[j + 2], c3 = col[j + 3];
        uint4 q0 = *(const uint4*)(hws + ((size_t)c0 << 7) + c8);
        uint4 q1 = *(const uint4*)(hws + ((size_t)c1 << 7) + c8);
        uint4 q2 = *(const uint4*)(hws + ((size_t)c2 << 7) + c8);
        uint4 q3 = *(const uint4*)(hws + ((size_t)c3 << 7) + c8);
        bfadd(A, q0); bfadd(B, q1); bfadd(A, q2); bfadd(B, q3);
    }
    for (; j < e; ++j) {
        int c = col[j];
        uint4 q = *(const uint4*)(hws + ((size_t)c << 7) + c8);
        bfadd(A, q);
    }
    uint4 qs = *(const uint4*)(hws + ((size_t)node << 7) + c8);
    bfadd(A, qs);
    float dv = dis[node];
    float4 bv0 = *(const float4*)(bias + c8);
    float4 bv1 = *(const float4*)(bias + c8 + 4);
    float r0 = fmaxf(dv * (A[0] + B[0]) + bv0.x, 0.f);
    float r1 = fmaxf(dv * (A[1] + B[1]) + bv0.y, 0.f);
    float r2 = fmaxf(dv * (A[2] + B[2]) + bv0.z, 0.f);
    float r3 = fmaxf(dv * (A[3] + B[3]) + bv0.w, 0.f);
    float r4 = fmaxf(dv * (A[4] + B[4]) + bv1.x, 0.f);
    float r5 = fmaxf(dv * (A[5] + B[5]) + bv1.y, 0.f);
    float r6 = fmaxf(dv * (A[6] + B[6]) + bv1.z, 0.f);
    float r7 = fmaxf(dv * (A[7] + B[7]) + bv1.w, 0.f);
    uint4 o;
    o.x = pack2(r0, r1);
    o.y = pack2(r2, r3);
    o.z = pack2(r4, r5);
    o.w = pack2(r6, r7);
    *(uint4*)(out + (size_t)node * 128 + c8) = o;
}

// ---------------- fused mean-pool + heads (bf16 h input) ----------------

__global__ __launch_bounds__(256) void k_pool_head(const ushort* __restrict__ h, const int* __restrict__ batch,
                                                   const float* __restrict__ Wmu, const float* __restrict__ bmu,
                                                   const float* __restrict__ Wlv, const float* __restrict__ blv,
                                                   float* __restrict__ out, int n) {
    int g = blockIdx.x;
    int t = threadIdx.x;
    int lo = 0, hi = n;
    while (lo < hi) { int m = (lo + hi) >> 1; if (batch[m] < g) lo = m + 1; else hi = m; }
    int start = lo;
    hi = n;
    while (lo < hi) { int m = (lo + hi) >> 1; if (batch[m] < g + 1) lo = m + 1; else hi = m; }
    int end = lo;

    __shared__ float sh0[256];
    __shared__ float sh1[256];
    __shared__ float pooled[128];
    int lane = t & 63;
    int grp = t >> 6;
    float a0 = 0.f, a1 = 0.f;
    for (int i = start + grp; i < end; i += 4) {
        uint q = *(const uint*)(h + (size_t)i * 128 + lane * 2);
        a0 += bf_lo(q);
        a1 += bf_hi(q);
    }
    sh0[t] = a0;
    sh1[t] = a1;
    __syncthreads();
    if (t < 64) {
        float cnt = (float)(end - start);
        float inv = 1.0f / fmaxf(cnt, 1.0f);
        float s0 = sh0[t] + sh0[t + 64] + sh0[t + 128] + sh0[t + 192];
        float s1 = sh1[t] + sh1[t + 64] + sh1[t + 128] + sh1[t + 192];
        pooled[t * 2] = s0 * inv;
        pooled[t * 2 + 1] = s1 * inv;
    }
    __syncthreads();
    float amu = bmu[t], alv = blv[t];
    for (int k = 0; k < 128; k += 4) {
        float p0 = pooled[k], p1 = pooled[k + 1], p2 = pooled[k + 2], p3 = pooled[k + 3];
        amu += p0 * Wmu[(k + 0) * 256 + t] + p1 * Wmu[(k + 1) * 256 + t]
             + p2 * Wmu[(k + 2) * 256 + t] + p3 * Wmu[(k + 3) * 256 + t];
        alv += p0 * Wlv[(k + 0) * 256 + t] + p1 * Wlv[(k + 1) * 256 + t]
             + p2 * Wlv[(k + 2) * 256 + t] + p3 * Wlv[(k + 3) * 256 + t];
    }
    out[(size_t)g * 256 + t] = amu;
    out[(size_t)N_GRAPHS * 256 + (size_t)g * 256 + t] = alv;
}

// ---------------- launch ----------------

extern "C" void kernel_launch(void* const* d_in, const int* in_sizes, int n_in,
                              void* d_out, int out_size, void* d_ws, size_t ws_size,
                              hipStream_t stream) {
    const float* x    = (const float*)d_in[0];
    const int*   eidx = (const int*)d_in[1];
    const int*   batch= (const int*)d_in[2];
    const float* W1   = (const float*)d_in[3];
    const float* b1   = (const float*)d_in[4];
    const float* W2   = (const float*)d_in[5];
    const float* b2   = (const float*)d_in[6];
    const float* W3   = (const float*)d_in[7];
    const float* b3   = (const float*)d_in[8];
    const float* Wmu  = (const float*)d_in[9];
    const float* bmu  = (const float*)d_in[10];
    const float* Wlv  = (const float*)d_in[11];
    const float* blv  = (const float*)d_in[12];
    float* out = (float*)d_out;

    const int N = N_NODES, E = N_EDGES;
    const int* srcp = eidx;
    const int* dstp = eidx + E;

    // workspace layout
    ushort* w1h = (ushort*)d_ws;            // 4096
    ushort* w1l = w1h + 4096;               // 4096
    ushort* w2h = w1l + 4096;               // 16384
    ushort* w2l = w2h + 16384;              // 16384
    ushort* w3h = w2l + 16384;              // 16384
    ushort* w3l = w3h + 16384;              // 16384
    ushort* A   = w3l + 16384;              // N*128 bf16 (hws, gathered)
    ushort* B   = A + (size_t)N * 128;      // N*128 bf16 (h)
    float*  dis = (float*)(B + (size_t)N * 128);  // N
    int*   rp   = (int*)(dis + N);          // N+1 (pad 2)
    int*   bktCnt   = rp + (N + 2);         // NB (pad 512)
    int*   colStart = bktCnt + 512;         // NB+1 (pad 512)
    int*   packed = colStart + 512;         // NB*CAP
    int*   col    = packed + (size_t)NB * CAP;  // E

    const int gE4096 = (E + 4095) / 4096;   // 782

    // W packs + bktCnt zeroing (one launch, runs before binA)
    k_pack_all<<<144, 256, 0, stream>>>(W1, W2, W3, w1h, w1l, w2h, w2l, w3h, w3l, bktCnt);

    // single-pass binned CSR build (wave-private histograms)
    k_binA<<<gE4096, 256, 0, stream>>>(srcp, dstp, bktCnt, packed, E);
    k_bscan<<<1, 512, 0, stream>>>(bktCnt, colStart);
    k_binB<<<NB, 256, 0, stream>>>(bktCnt, colStart, packed, col, rp, dis, N);

    const int gGemm = (N + 63) / 64;
    const int gAgg  = (N + 15) / 16;

    k_gemm_mfma_f32<<<gGemm, 256, 0, stream>>>(x, w1h, w1l, dis, A, N);
    k_agg<<<gAgg, 256, 0, stream>>>(A, rp, col, dis, b1, B, N);
    k_gemm_mfma_bf<<<gGemm, 256, 0, stream>>>(B, w2h, w2l, dis, A, N);
    k_agg<<<gAgg, 256, 0, stream>>>(A, rp, col, dis, b2, B, N);
    k_gemm_mfma_bf<<<gGemm, 256, 0, stream>>>(B, w3h, w3l, dis, A, N);
    k_agg<<<gAgg, 256, 0, stream>>>(A, rp, col, dis, b3, B, N);
    k_pool_head<<<N_GRAPHS, 256, 0, stream>>>(B, batch, Wmu, bmu, Wlv, blv, out, N);
}

// Round 14
// 587.434 us; speedup vs baseline: 1.0268x; 1.0268x over previous
//
#include <hip/hip_runtime.h>
#include <hip/hip_bf16.h>

#define N_NODES 100000
#define N_EDGES 3200000
#define N_GRAPHS 512
#define IN_DIM 29
#define HID 128
#define LAT 256
#define NB 391     // ceil(N_NODES/256) dst-buckets
#define CAP 9216   // per-bucket packed capacity (mean 8184, sigma~90 -> +11 sigma)

typedef unsigned int uint;
typedef unsigned short ushort;
typedef float v4f __attribute__((ext_vector_type(4)));
typedef short v8s __attribute__((ext_vector_type(8)));

// round-to-nearest-even fp32 -> bf16 (finite inputs)
__device__ __forceinline__ ushort f2bf(float f) {
    uint u = __float_as_uint(f);
    return (ushort)((u + 0x7FFFu + ((u >> 16) & 1u)) >> 16);
}
__device__ __forceinline__ float bf2f(ushort h) { return __uint_as_float(((uint)h) << 16); }
__device__ __forceinline__ float bf_lo(uint p) { return __uint_as_float(p << 16); }
__device__ __forceinline__ float bf_hi(uint p) { return __uint_as_float(p & 0xFFFF0000u); }
__device__ __forceinline__ uint pack2(float a, float b) {
    return (uint)f2bf(a) | ((uint)f2bf(b) << 16);
}

__device__ __forceinline__ void bfadd(float* a, uint4 q) {
    a[0] += bf_lo(q.x); a[1] += bf_hi(q.x);
    a[2] += bf_lo(q.y); a[3] += bf_hi(q.y);
    a[4] += bf_lo(q.z); a[5] += bf_hi(q.z);
    a[6] += bf_lo(q.w); a[7] += bf_hi(q.w);
}

// ---------------- preprocessing ----------------

// Single-pass binning: 512 threads x 8 edges. bin edges by dst>>8 into
// fixed-stride CAP regions. pack (dst&255)<<17 | src.
__global__ __launch_bounds__(512, 4) void k_binA(const int* __restrict__ src, const int* __restrict__ dst,
                                                 int* __restrict__ bktCnt, int* __restrict__ packed, int e) {
    __shared__ int hist[NB];
    __shared__ int base[NB];
    int t = threadIdx.x;
    for (int i = t; i < NB; i += 512) hist[i] = 0;
    __syncthreads();
    int d[8], s[8];
    const int blockStart = blockIdx.x * 4096;
    #pragma unroll
    for (int k = 0; k < 8; ++k) {
        int idx = blockStart + k * 512 + t;
        if (idx < e) {
            d[k] = dst[idx];
            s[k] = src[idx];
            atomicAdd(&hist[d[k] >> 8], 1);
        } else d[k] = -1;
    }
    __syncthreads();
    for (int i = t; i < NB; i += 512) {
        int c = hist[i];
        base[i] = c ? atomicAdd(&bktCnt[i], c) : 0;   // bucket-local offset
    }
    __syncthreads();
    #pragma unroll
    for (int k = 0; k < 8; ++k) {
        if (d[k] >= 0) {
            int b = d[k] >> 8;
            int pos = atomicAdd(&base[b], 1);
            if (pos < CAP) packed[b * CAP + pos] = ((d[k] & 255) << 17) | s[k];
        }
    }
}

// single block: exclusive scan of bktCnt -> colStart[NB+1] (dense col layout)
__global__ __launch_bounds__(512) void k_bscan(const int* __restrict__ bktCnt, int* __restrict__ colStart) {
    __shared__ int sh[512];
    int t = threadIdx.x;
    int v = (t < NB) ? bktCnt[t] : 0;
    if (v > CAP) v = CAP;
    sh[t] = v;
    __syncthreads();
    for (int off = 1; off < 512; off <<= 1) {
        int x = (t >= off) ? sh[t - off] : 0;
        __syncthreads();
        sh[t] += x;
        __syncthreads();
    }
    int excl = sh[t] - v;
    if (t <= NB) colStart[t] = excl;
}

// Phase B: per bucket, 1024 threads. Stage the bucket's packed segment in LDS
// (single HBM read), count per-node degrees, scan -> rp & dis (coalesced),
// scatter col from LDS to final dense CSR positions (L2-resident region).
__global__ __launch_bounds__(1024, 2) void k_binB(const int* __restrict__ bktCnt, const int* __restrict__ colStart,
                                                  const int* __restrict__ packed, int* __restrict__ col,
                                                  int* __restrict__ rp, float* __restrict__ dis, int n) {
    __shared__ int seg[CAP];
    __shared__ int cnt[256];
    __shared__ int sh[256];
    __shared__ int cur[256];
    const int b = blockIdx.x;
    int cntB = bktCnt[b];
    if (cntB > CAP) cntB = CAP;
    const int segS = b * CAP;
    const int colBase = colStart[b];
    int t = threadIdx.x;
    if (t < 256) cnt[t] = 0;
    __syncthreads();
    for (int j = t; j < cntB; j += 1024) {
        int pk = packed[segS + j];
        seg[j] = pk;
        atomicAdd(&cnt[pk >> 17], 1);
    }
    __syncthreads();
    int v = (t < 256) ? cnt[t] : 0;
    if (t < 256) sh[t] = v;
    __syncthreads();
    for (int off = 1; off < 256; off <<= 1) {
        int x = (t < 256 && t >= off) ? sh[t - off] : 0;
        __syncthreads();
        if (t < 256) sh[t] += x;
        __syncthreads();
    }
    if (t < 256) {
        int excl = sh[t] - v;
        int node = (b << 8) + t;
        int start = colBase + excl;
        cur[t] = start;
        if (node <= n) rp[node] = start;      // node==n (last bucket) -> rp[n] = E
        if (node < n) dis[node] = rsqrtf((float)v + 1.0f);
    }
    __syncthreads();
    for (int j = t; j < cntB; j += 1024) {
        int pk = seg[j];
        int dl = pk >> 17;
        int pos = atomicAdd(&cur[dl], 1);
        col[pos] = pk & 0x1FFFF;
    }
}

// ---------------- W pack (all 3 layers) + zero bktCnt (runs first) ----------------
// layout index = ((kstep*8 + ntile)*64 + lane)*8 + j
// element = W[kstep*32 + (lane>>4)*8 + j][ntile*16 + (lane&15)]

__device__ __forceinline__ void pack_one(const float* W, ushort* hi, ushort* lo, int Ksrc, int idx) {
    int j = idx & 7;
    int lane = (idx >> 3) & 63;
    int nt = (idx >> 9) & 7;
    int ks = idx >> 12;
    int k = ks * 32 + (lane >> 4) * 8 + j;
    int n = nt * 16 + (lane & 15);
    float v = (k < Ksrc) ? W[k * 128 + n] : 0.f;
    ushort h = f2bf(v);
    ushort l = f2bf(v - bf2f(h));
    hi[idx] = h;
    lo[idx] = l;
}

__global__ __launch_bounds__(256) void k_pack_all(const float* __restrict__ W1, const float* __restrict__ W2,
                                                  const float* __restrict__ W3,
                                                  ushort* w1h, ushort* w1l, ushort* w2h, ushort* w2l,
                                                  ushort* w3h, ushort* w3l, int* __restrict__ bktCnt) {
    int idx = blockIdx.x * 256 + threadIdx.x;
    if (idx < NB) bktCnt[idx] = 0;        // fold the zeroing launch in here
    if (idx < 4096) {
        pack_one(W1, w1h, w1l, IN_DIM, idx);
    } else if (idx < 4096 + 16384) {
        pack_one(W2, w2h, w2l, HID, idx - 4096);
    } else if (idx < 4096 + 32768) {
        pack_one(W3, w3h, w3l, HID, idx - 4096 - 16384);
    }
}

// ---------------- MFMA GEMM (layer 1): hws = dis * (x_f32 @ W) ----------------
// Split precision: acc = Ahi@Whi + Ahi@Wlo + Alo@Whi.

__global__ __launch_bounds__(256, 6) void k_gemm_mfma_f32(const float* __restrict__ in,
                                                          const ushort* __restrict__ Whi,
                                                          const ushort* __restrict__ Wlo,
                                                          const float* __restrict__ dis,
                                                          ushort* __restrict__ out, int n) {
    const int wave = threadIdx.x >> 6;
    const int lane = threadIdx.x & 63;
    const int m0 = (blockIdx.x * 4 + wave) * 16;
    if (m0 >= n) return;
    int row = m0 + (lane & 15);
    if (row >= n) row = n - 1;
    const int kh = (lane >> 4) * 8;
    const float* rptr = in + (size_t)row * IN_DIM + kh;

    v4f acc[8];
    #pragma unroll
    for (int t = 0; t < 8; ++t) acc[t] = (v4f){0.f, 0.f, 0.f, 0.f};

    float a[8];
    #pragma unroll
    for (int j = 0; j < 8; ++j) a[j] = (kh + j < IN_DIM) ? rptr[j] : 0.f;
    v8s ahi, alo;
    #pragma unroll
    for (int j = 0; j < 8; ++j) {
        ushort h = f2bf(a[j]);
        ushort l = f2bf(a[j] - bf2f(h));
        ahi[j] = (short)h;
        alo[j] = (short)l;
    }
    const ushort* bh = Whi + (size_t)lane * 8;
    const ushort* bl = Wlo + (size_t)lane * 8;
    #pragma unroll
    for (int nt = 0; nt < 8; ++nt) {
        v8s bhi = *(const v8s*)(bh + nt * 512);
        v8s blo = *(const v8s*)(bl + nt * 512);
        acc[nt] = __builtin_amdgcn_mfma_f32_16x16x32_bf16(ahi, bhi, acc[nt], 0, 0, 0);
        acc[nt] = __builtin_amdgcn_mfma_f32_16x16x32_bf16(ahi, blo, acc[nt], 0, 0, 0);
        acc[nt] = __builtin_amdgcn_mfma_f32_16x16x32_bf16(alo, bhi, acc[nt], 0, 0, 0);
    }

    const int orow0 = m0 + (lane >> 4) * 4;
    const int col0 = lane & 15;
    #pragma unroll
    for (int r = 0; r < 4; ++r) {
        int orow = orow0 + r;
        if (orow < n) {
            float dv = dis[orow];
            #pragma unroll
            for (int nt = 0; nt < 8; ++nt)
                out[(size_t)orow * 128 + nt * 16 + col0] = f2bf(acc[nt][r] * dv);
        }
    }
}

// ---------------- MFMA GEMM (layers 2,3): hws = dis * (h_bf16 @ W) ----------------
// A exact bf16 -> 2 MFMAs: A@Whi + A@Wlo.

__global__ __launch_bounds__(256, 6) void k_gemm_mfma_bf(const ushort* __restrict__ in,
                                                         const ushort* __restrict__ Whi,
                                                         const ushort* __restrict__ Wlo,
                                                         const float* __restrict__ dis,
                                                         ushort* __restrict__ out, int n) {
    const int wave = threadIdx.x >> 6;
    const int lane = threadIdx.x & 63;
    const int m0 = (blockIdx.x * 4 + wave) * 16;
    if (m0 >= n) return;
    int row = m0 + (lane & 15);
    if (row >= n) row = n - 1;
    const int kh = (lane >> 4) * 8;
    const ushort* rptr = in + (size_t)row * 128 + kh;

    v4f acc[8];
    #pragma unroll
    for (int t = 0; t < 8; ++t) acc[t] = (v4f){0.f, 0.f, 0.f, 0.f};

    #pragma unroll
    for (int ks = 0; ks < 4; ++ks) {
        v8s a = *(const v8s*)(rptr + ks * 32);
        const ushort* bh = Whi + (size_t)(ks * 8) * 512 + (size_t)lane * 8;
        const ushort* bl = Wlo + (size_t)(ks * 8) * 512 + (size_t)lane * 8;
        #pragma unroll
        for (int nt = 0; nt < 8; ++nt) {
            v8s bhi = *(const v8s*)(bh + nt * 512);
            v8s blo = *(const v8s*)(bl + nt * 512);
            acc[nt] = __builtin_amdgcn_mfma_f32_16x16x32_bf16(a, bhi, acc[nt], 0, 0, 0);
            acc[nt] = __builtin_amdgcn_mfma_f32_16x16x32_bf16(a, blo, acc[nt], 0, 0, 0);
        }
    }

    const int orow0 = m0 + (lane >> 4) * 4;
    const int col0 = lane & 15;
    #pragma unroll
    for (int r = 0; r < 4; ++r) {
        int orow = orow0 + r;
        if (orow < n) {
            float dv = dis[orow];
            #pragma unroll
            for (int nt = 0; nt < 8; ++nt)
                out[(size_t)orow * 128 + nt * 16 + col0] = f2bf(acc[nt][r] * dv);
        }
    }
}

// ---------------- aggregation (R9-exact): 16 lanes/node, 8 ch/lane, 4 edges in flight ----------------
// out[i][:] = bf16( relu( dis[i] * ( sum_j hws[col[j]][:] + hws[i][:] ) + b[:] ) )

__global__ __launch_bounds__(256, 8) void k_agg(const ushort* __restrict__ hws, const int* __restrict__ rp,
                                                const int* __restrict__ col, const float* __restrict__ dis,
                                                const float* __restrict__ bias, ushort* __restrict__ out, int n) {
    int node = (int)((blockIdx.x * 256 + threadIdx.x) >> 4);
    if (node >= n) return;
    int c8 = (threadIdx.x & 15) << 3;
    int s = rp[node], e = rp[node + 1];
    float A[8] = {0.f, 0.f, 0.f, 0.f, 0.f, 0.f, 0.f, 0.f};
    float B[8] = {0.f, 0.f, 0.f, 0.f, 0.f, 0.f, 0.f, 0.f};
    int j = s;
    for (; j + 3 < e; j += 4) {
        int c0 = col[j], c1 = col[j + 1], c2 = col[j + 2], c3 = col[j + 3];
        uint4 q0 = *(const uint4*)(hws + ((size_t)c0 << 7) + c8);
        uint4 q1 = *(const uint4*)(hws + ((size_t)c1 << 7) + c8);
        uint4 q2 = *(const uint4*)(hws + ((size_t)c2 << 7) + c8);
        uint4 q3 = *(const uint4*)(hws + ((size_t)c3 << 7) + c8);
        bfadd(A, q0); bfadd(B, q1); bfadd(A, q2); bfadd(B, q3);
    }
    for (; j < e; ++j) {
        int c = col[j];
        uint4 q = *(const uint4*)(hws + ((size_t)c << 7) + c8);
        bfadd(A, q);
    }
    uint4 qs = *(const uint4*)(hws + ((size_t)node << 7) + c8);
    bfadd(A, qs);
    float dv = dis[node];
    float4 bv0 = *(const float4*)(bias + c8);
    float4 bv1 = *(const float4*)(bias + c8 + 4);
    float r0 = fmaxf(dv * (A[0] + B[0]) + bv0.x, 0.f);
    float r1 = fmaxf(dv * (A[1] + B[1]) + bv0.y, 0.f);
    float r2 = fmaxf(dv * (A[2] + B[2]) + bv0.z, 0.f);
    float r3 = fmaxf(dv * (A[3] + B[3]) + bv0.w, 0.f);
    float r4 = fmaxf(dv * (A[4] + B[4]) + bv1.x, 0.f);
    float r5 = fmaxf(dv * (A[5] + B[5]) + bv1.y, 0.f);
    float r6 = fmaxf(dv * (A[6] + B[6]) + bv1.z, 0.f);
    float r7 = fmaxf(dv * (A[7] + B[7]) + bv1.w, 0.f);
    uint4 o;
    o.x = pack2(r0, r1);
    o.y = pack2(r2, r3);
    o.z = pack2(r4, r5);
    o.w = pack2(r6, r7);
    *(uint4*)(out + (size_t)node * 128 + c8) = o;
}

// ---------------- fused mean-pool + heads (bf16 h input) ----------------

__global__ __launch_bounds__(256) void k_pool_head(const ushort* __restrict__ h, const int* __restrict__ batch,
                                                   const float* __restrict__ Wmu, const float* __restrict__ bmu,
                                                   const float* __restrict__ Wlv, const float* __restrict__ blv,
                                                   float* __restrict__ out, int n) {
    int g = blockIdx.x;
    int t = threadIdx.x;
    int lo = 0, hi = n;
    while (lo < hi) { int m = (lo + hi) >> 1; if (batch[m] < g) lo = m + 1; else hi = m; }
    int start = lo;
    hi = n;
    while (lo < hi) { int m = (lo + hi) >> 1; if (batch[m] < g + 1) lo = m + 1; else hi = m; }
    int end = lo;

    __shared__ float sh0[256];
    __shared__ float sh1[256];
    __shared__ float pooled[128];
    int lane = t & 63;
    int grp = t >> 6;
    float a0 = 0.f, a1 = 0.f;
    for (int i = start + grp; i < end; i += 4) {
        uint q = *(const uint*)(h + (size_t)i * 128 + lane * 2);
        a0 += bf_lo(q);
        a1 += bf_hi(q);
    }
    sh0[t] = a0;
    sh1[t] = a1;
    __syncthreads();
    if (t < 64) {
        float cnt = (float)(end - start);
        float inv = 1.0f / fmaxf(cnt, 1.0f);
        float s0 = sh0[t] + sh0[t + 64] + sh0[t + 128] + sh0[t + 192];
        float s1 = sh1[t] + sh1[t + 64] + sh1[t + 128] + sh1[t + 192];
        pooled[t * 2] = s0 * inv;
        pooled[t * 2 + 1] = s1 * inv;
    }
    __syncthreads();
    float amu = bmu[t], alv = blv[t];
    for (int k = 0; k < 128; k += 4) {
        float p0 = pooled[k], p1 = pooled[k + 1], p2 = pooled[k + 2], p3 = pooled[k + 3];
        amu += p0 * Wmu[(k + 0) * 256 + t] + p1 * Wmu[(k + 1) * 256 + t]
             + p2 * Wmu[(k + 2) * 256 + t] + p3 * Wmu[(k + 3) * 256 + t];
        alv += p0 * Wlv[(k + 0) * 256 + t] + p1 * Wlv[(k + 1) * 256 + t]
             + p2 * Wlv[(k + 2) * 256 + t] + p3 * Wlv[(k + 3) * 256 + t];
    }
    out[(size_t)g * 256 + t] = amu;
    out[(size_t)N_GRAPHS * 256 + (size_t)g * 256 + t] = alv;
}

// ---------------- launch ----------------

extern "C" void kernel_launch(void* const* d_in, const int* in_sizes, int n_in,
                              void* d_out, int out_size, void* d_ws, size_t ws_size,
                              hipStream_t stream) {
    const float* x    = (const float*)d_in[0];
    const int*   eidx = (const int*)d_in[1];
    const int*   batch= (const int*)d_in[2];
    const float* W1   = (const float*)d_in[3];
    const float* b1   = (const float*)d_in[4];
    const float* W2   = (const float*)d_in[5];
    const float* b2   = (const float*)d_in[6];
    const float* W3   = (const float*)d_in[7];
    const float* b3   = (const float*)d_in[8];
    const float* Wmu  = (const float*)d_in[9];
    const float* bmu  = (const float*)d_in[10];
    const float* Wlv  = (const float*)d_in[11];
    const float* blv  = (const float*)d_in[12];
    float* out = (float*)d_out;

    const int N = N_NODES, E = N_EDGES;
    const int* srcp = eidx;
    const int* dstp = eidx + E;

    // workspace layout
    ushort* w1h = (ushort*)d_ws;            // 4096
    ushort* w1l = w1h + 4096;               // 4096
    ushort* w2h = w1l + 4096;               // 16384
    ushort* w2l = w2h + 16384;              // 16384
    ushort* w3h = w2l + 16384;              // 16384
    ushort* w3l = w3h + 16384;              // 16384
    ushort* A   = w3l + 16384;              // N*128 bf16 (hws, gathered)
    ushort* B   = A + (size_t)N * 128;      // N*128 bf16 (h)
    float*  dis = (float*)(B + (size_t)N * 128);  // N
    int*   rp   = (int*)(dis + N);          // N+1 (pad 2)
    int*   bktCnt   = rp + (N + 2);         // NB (pad 512)
    int*   colStart = bktCnt + 512;         // NB+1 (pad 512)
    int*   packed = colStart + 512;         // NB*CAP
    int*   col    = packed + (size_t)NB * CAP;  // E

    const int gE4096 = (E + 4095) / 4096;   // 782

    // W packs + bktCnt zeroing (one launch, runs before binA)
    k_pack_all<<<144, 256, 0, stream>>>(W1, W2, W3, w1h, w1l, w2h, w2l, w3h, w3l, bktCnt);

    // single-pass binned CSR build
    k_binA<<<gE4096, 512, 0, stream>>>(srcp, dstp, bktCnt, packed, E);
    k_bscan<<<1, 512, 0, stream>>>(bktCnt, colStart);
    k_binB<<<NB, 1024, 0, stream>>>(bktCnt, colStart, packed, col, rp, dis, N);

    const int gGemm = (N + 63) / 64;
    const int gAgg  = (N + 15) / 16;

    k_gemm_mfma_f32<<<gGemm, 256, 0, stream>>>(x, w1h, w1l, dis, A, N);
    k_agg<<<gAgg, 256, 0, stream>>>(A, rp, col, dis, b1, B, N);
    k_gemm_mfma_bf<<<gGemm, 256, 0, stream>>>(B, w2h, w2l, dis, A, N);
    k_agg<<<gAgg, 256, 0, stream>>>(A, rp, col, dis, b2, B, N);
    k_gemm_mfma_bf<<<gGemm, 256, 0, stream>>>(B, w3h, w3l, dis, A, N);
    k_agg<<<gAgg, 256, 0, stream>>>(A, rp, col, dis, b3, B, N);
    k_pool_head<<<N_GRAPHS, 256, 0, stream>>>(B, batch, Wmu, bmu, Wlv, blv, out, N);
}

// Round 15
// 573.630 us; speedup vs baseline: 1.0515x; 1.0241x over previous
//
#include <hip/hip_runtime.h>
#include <hip/hip_bf16.h>

#define N_NODES 100000
#define N_EDGES 3200000
#define N_GRAPHS 512
#define IN_DIM 29
#define HID 128
#define LAT 256
#define NB 391     // ceil(N_NODES/256) dst-buckets
#define CAP 9216   // per-bucket packed capacity (mean 8184, sigma~90 -> +11 sigma)

typedef unsigned int uint;
typedef unsigned short ushort;
typedef float v4f __attribute__((ext_vector_type(4)));
typedef short v8s __attribute__((ext_vector_type(8)));

// round-to-nearest-even fp32 -> bf16 (finite inputs)
__device__ __forceinline__ ushort f2bf(float f) {
    uint u = __float_as_uint(f);
    return (ushort)((u + 0x7FFFu + ((u >> 16) & 1u)) >> 16);
}
__device__ __forceinline__ float bf2f(ushort h) { return __uint_as_float(((uint)h) << 16); }
__device__ __forceinline__ float bf_lo(uint p) { return __uint_as_float(p << 16); }
__device__ __forceinline__ float bf_hi(uint p) { return __uint_as_float(p & 0xFFFF0000u); }
__device__ __forceinline__ uint pack2(float a, float b) {
    return (uint)f2bf(a) | ((uint)f2bf(b) << 16);
}

__device__ __forceinline__ void bfadd(float* a, uint4 q) {
    a[0] += bf_lo(q.x); a[1] += bf_hi(q.x);
    a[2] += bf_lo(q.y); a[3] += bf_hi(q.y);
    a[4] += bf_lo(q.z); a[5] += bf_hi(q.z);
    a[6] += bf_lo(q.w); a[7] += bf_hi(q.w);
}

// ---------------- preprocessing ----------------

// Single-pass binning: 512 threads x 8 edges. bin edges by dst>>8 into
// fixed-stride CAP regions. pack (dst&255)<<17 | src.
__global__ __launch_bounds__(512, 4) void k_binA(const int* __restrict__ src, const int* __restrict__ dst,
                                                 int* __restrict__ bktCnt, int* __restrict__ packed, int e) {
    __shared__ int hist[NB];
    __shared__ int base[NB];
    int t = threadIdx.x;
    for (int i = t; i < NB; i += 512) hist[i] = 0;
    __syncthreads();
    int d[8], s[8];
    const int blockStart = blockIdx.x * 4096;
    #pragma unroll
    for (int k = 0; k < 8; ++k) {
        int idx = blockStart + k * 512 + t;
        if (idx < e) {
            d[k] = dst[idx];
            s[k] = src[idx];
            atomicAdd(&hist[d[k] >> 8], 1);
        } else d[k] = -1;
    }
    __syncthreads();
    for (int i = t; i < NB; i += 512) {
        int c = hist[i];
        base[i] = c ? atomicAdd(&bktCnt[i], c) : 0;   // bucket-local offset
    }
    __syncthreads();
    #pragma unroll
    for (int k = 0; k < 8; ++k) {
        if (d[k] >= 0) {
            int b = d[k] >> 8;
            int pos = atomicAdd(&base[b], 1);
            if (pos < CAP) packed[b * CAP + pos] = ((d[k] & 255) << 17) | s[k];
        }
    }
}

// single block: exclusive scan of bktCnt -> colStart[NB+1] (dense col layout)
__global__ __launch_bounds__(512) void k_bscan(const int* __restrict__ bktCnt, int* __restrict__ colStart) {
    __shared__ int sh[512];
    int t = threadIdx.x;
    int v = (t < NB) ? bktCnt[t] : 0;
    if (v > CAP) v = CAP;
    sh[t] = v;
    __syncthreads();
    for (int off = 1; off < 512; off <<= 1) {
        int x = (t >= off) ? sh[t - off] : 0;
        __syncthreads();
        sh[t] += x;
        __syncthreads();
    }
    int excl = sh[t] - v;
    if (t <= NB) colStart[t] = excl;
}

// Phase B: per bucket, 1024 threads. Stage the bucket's packed segment in LDS,
// count per-(node, src-segment) keys (seg = src>>13, 13 live segments, padded 16),
// scan the 4096 keys -> rp & dis (coalesced) + per-key cursors, then scatter col
// from LDS grouped by (node, seg) with seg ascending. This makes k_agg's gather
// walk src-ranges in phase across the whole chip -> L2 working set ~2 segments
// (~4 MB) instead of 25.6 MB. k_agg itself is unchanged.
__global__ __launch_bounds__(1024, 2) void k_binB(const int* __restrict__ bktCnt, const int* __restrict__ colStart,
                                                  const int* __restrict__ packed, int* __restrict__ col,
                                                  int* __restrict__ rp, float* __restrict__ dis, int n) {
    __shared__ int seg[CAP];      // 36 KB staged packed edges
    __shared__ int cnt[4096];     // 16 KB: per-(node,seg) counts -> cursors
    __shared__ int sh[1024];      // 4 KB: block scan of 1024 partial sums
    const int b = blockIdx.x;
    int cntB = bktCnt[b];
    if (cntB > CAP) cntB = CAP;
    const int segS = b * CAP;
    const int colBase = colStart[b];
    int t = threadIdx.x;
    cnt[t] = 0; cnt[t + 1024] = 0; cnt[t + 2048] = 0; cnt[t + 3072] = 0;
    __syncthreads();
    for (int j = t; j < cntB; j += 1024) {
        int pk = packed[segS + j];
        seg[j] = pk;
        int key = ((pk >> 17) << 4) | ((pk & 0x1FFFF) >> 13);
        atomicAdd(&cnt[key], 1);
    }
    __syncthreads();
    // exclusive scan of cnt[4096]: thread t owns keys [4t, 4t+4)
    int base4 = t << 2;
    int v0 = cnt[base4], v1 = cnt[base4 + 1], v2 = cnt[base4 + 2], v3 = cnt[base4 + 3];
    int sum = v0 + v1 + v2 + v3;
    sh[t] = sum;
    __syncthreads();
    for (int off = 1; off < 1024; off <<= 1) {
        int x = (t >= off) ? sh[t - off] : 0;
        __syncthreads();
        sh[t] += x;
        __syncthreads();
    }
    int excl = sh[t] - sum;
    cnt[base4]     = colBase + excl;
    cnt[base4 + 1] = colBase + excl + v0;
    cnt[base4 + 2] = colBase + excl + v0 + v1;
    cnt[base4 + 3] = colBase + excl + v0 + v1 + v2;
    __syncthreads();
    if (t < 256) {
        int node = (b << 8) + t;
        int start = cnt[t << 4];
        int next = (t == 255) ? (colBase + cntB) : cnt[(t + 1) << 4];
        int deg = next - start;
        if (node <= n) rp[node] = start;      // node==n (last bucket) -> rp[n] = E
        if (node < n) dis[node] = rsqrtf((float)deg + 1.0f);
    }
    __syncthreads();
    for (int j = t; j < cntB; j += 1024) {
        int pk = seg[j];
        int key = ((pk >> 17) << 4) | ((pk & 0x1FFFF) >> 13);
        int pos = atomicAdd(&cnt[key], 1);
        col[pos] = pk & 0x1FFFF;
    }
}

// ---------------- W pack (all 3 layers) + zero bktCnt (runs first) ----------------
// layout index = ((kstep*8 + ntile)*64 + lane)*8 + j
// element = W[kstep*32 + (lane>>4)*8 + j][ntile*16 + (lane&15)]

__device__ __forceinline__ void pack_one(const float* W, ushort* hi, ushort* lo, int Ksrc, int idx) {
    int j = idx & 7;
    int lane = (idx >> 3) & 63;
    int nt = (idx >> 9) & 7;
    int ks = idx >> 12;
    int k = ks * 32 + (lane >> 4) * 8 + j;
    int n = nt * 16 + (lane & 15);
    float v = (k < Ksrc) ? W[k * 128 + n] : 0.f;
    ushort h = f2bf(v);
    ushort l = f2bf(v - bf2f(h));
    hi[idx] = h;
    lo[idx] = l;
}

__global__ __launch_bounds__(256) void k_pack_all(const float* __restrict__ W1, const float* __restrict__ W2,
                                                  const float* __restrict__ W3,
                                                  ushort* w1h, ushort* w1l, ushort* w2h, ushort* w2l,
                                                  ushort* w3h, ushort* w3l, int* __restrict__ bktCnt) {
    int idx = blockIdx.x * 256 + threadIdx.x;
    if (idx < NB) bktCnt[idx] = 0;        // fold the zeroing launch in here
    if (idx < 4096) {
        pack_one(W1, w1h, w1l, IN_DIM, idx);
    } else if (idx < 4096 + 16384) {
        pack_one(W2, w2h, w2l, HID, idx - 4096);
    } else if (idx < 4096 + 32768) {
        pack_one(W3, w3h, w3l, HID, idx - 4096 - 16384);
    }
}

// ---------------- MFMA GEMM (layer 1): hws = dis * (x_f32 @ W) ----------------
// Split precision: acc = Ahi@Whi + Ahi@Wlo + Alo@Whi.

__global__ __launch_bounds__(256, 6) void k_gemm_mfma_f32(const float* __restrict__ in,
                                                          const ushort* __restrict__ Whi,
                                                          const ushort* __restrict__ Wlo,
                                                          const float* __restrict__ dis,
                                                          ushort* __restrict__ out, int n) {
    const int wave = threadIdx.x >> 6;
    const int lane = threadIdx.x & 63;
    const int m0 = (blockIdx.x * 4 + wave) * 16;
    if (m0 >= n) return;
    int row = m0 + (lane & 15);
    if (row >= n) row = n - 1;
    const int kh = (lane >> 4) * 8;
    const float* rptr = in + (size_t)row * IN_DIM + kh;

    v4f acc[8];
    #pragma unroll
    for (int t = 0; t < 8; ++t) acc[t] = (v4f){0.f, 0.f, 0.f, 0.f};

    float a[8];
    #pragma unroll
    for (int j = 0; j < 8; ++j) a[j] = (kh + j < IN_DIM) ? rptr[j] : 0.f;
    v8s ahi, alo;
    #pragma unroll
    for (int j = 0; j < 8; ++j) {
        ushort h = f2bf(a[j]);
        ushort l = f2bf(a[j] - bf2f(h));
        ahi[j] = (short)h;
        alo[j] = (short)l;
    }
    const ushort* bh = Whi + (size_t)lane * 8;
    const ushort* bl = Wlo + (size_t)lane * 8;
    #pragma unroll
    for (int nt = 0; nt < 8; ++nt) {
        v8s bhi = *(const v8s*)(bh + nt * 512);
        v8s blo = *(const v8s*)(bl + nt * 512);
        acc[nt] = __builtin_amdgcn_mfma_f32_16x16x32_bf16(ahi, bhi, acc[nt], 0, 0, 0);
        acc[nt] = __builtin_amdgcn_mfma_f32_16x16x32_bf16(ahi, blo, acc[nt], 0, 0, 0);
        acc[nt] = __builtin_amdgcn_mfma_f32_16x16x32_bf16(alo, bhi, acc[nt], 0, 0, 0);
    }

    const int orow0 = m0 + (lane >> 4) * 4;
    const int col0 = lane & 15;
    #pragma unroll
    for (int r = 0; r < 4; ++r) {
        int orow = orow0 + r;
        if (orow < n) {
            float dv = dis[orow];
            #pragma unroll
            for (int nt = 0; nt < 8; ++nt)
                out[(size_t)orow * 128 + nt * 16 + col0] = f2bf(acc[nt][r] * dv);
        }
    }
}

// ---------------- MFMA GEMM (layers 2,3): hws = dis * (h_bf16 @ W) ----------------
// A exact bf16 -> 2 MFMAs: A@Whi + A@Wlo.

__global__ __launch_bounds__(256, 6) void k_gemm_mfma_bf(const ushort* __restrict__ in,
                                                         const ushort* __restrict__ Whi,
                                                         const ushort* __restrict__ Wlo,
                                                         const float* __restrict__ dis,
                                                         ushort* __restrict__ out, int n) {
    const int wave = threadIdx.x >> 6;
    const int lane = threadIdx.x & 63;
    const int m0 = (blockIdx.x * 4 + wave) * 16;
    if (m0 >= n) return;
    int row = m0 + (lane & 15);
    if (row >= n) row = n - 1;
    const int kh = (lane >> 4) * 8;
    const ushort* rptr = in + (size_t)row * 128 + kh;

    v4f acc[8];
    #pragma unroll
    for (int t = 0; t < 8; ++t) acc[t] = (v4f){0.f, 0.f, 0.f, 0.f};

    #pragma unroll
    for (int ks = 0; ks < 4; ++ks) {
        v8s a = *(const v8s*)(rptr + ks * 32);
        const ushort* bh = Whi + (size_t)(ks * 8) * 512 + (size_t)lane * 8;
        const ushort* bl = Wlo + (size_t)(ks * 8) * 512 + (size_t)lane * 8;
        #pragma unroll
        for (int nt = 0; nt < 8; ++nt) {
            v8s bhi = *(const v8s*)(bh + nt * 512);
            v8s blo = *(const v8s*)(bl + nt * 512);
            acc[nt] = __builtin_amdgcn_mfma_f32_16x16x32_bf16(a, bhi, acc[nt], 0, 0, 0);
            acc[nt] = __builtin_amdgcn_mfma_f32_16x16x32_bf16(a, blo, acc[nt], 0, 0, 0);
        }
    }

    const int orow0 = m0 + (lane >> 4) * 4;
    const int col0 = lane & 15;
    #pragma unroll
    for (int r = 0; r < 4; ++r) {
        int orow = orow0 + r;
        if (orow < n) {
            float dv = dis[orow];
            #pragma unroll
            for (int nt = 0; nt < 8; ++nt)
                out[(size_t)orow * 128 + nt * 16 + col0] = f2bf(acc[nt][r] * dv);
        }
    }
}

// ---------------- aggregation (R9/R14-exact): 16 lanes/node, 8 ch/lane, 4 edges in flight ----------------
// out[i][:] = bf16( relu( dis[i] * ( sum_j hws[col[j]][:] + hws[i][:] ) + b[:] ) )

__global__ __launch_bounds__(256, 8) void k_agg(const ushort* __restrict__ hws, const int* __restrict__ rp,
                                                const int* __restrict__ col, const float* __restrict__ dis,
                                                const float* __restrict__ bias, ushort* __restrict__ out, int n) {
    int node = (int)((blockIdx.x * 256 + threadIdx.x) >> 4);
    if (node >= n) return;
    int c8 = (threadIdx.x & 15) << 3;
    int s = rp[node], e = rp[node + 1];
    float A[8] = {0.f, 0.f, 0.f, 0.f, 0.f, 0.f, 0.f, 0.f};
    float B[8] = {0.f, 0.f, 0.f, 0.f, 0.f, 0.f, 0.f, 0.f};
    int j = s;
    for (; j + 3 < e; j += 4) {
        int c0 = col[j], c1 = col[j + 1], c2 = col[j + 2], c3 = col[j + 3];
        uint4 q0 = *(const uint4*)(hws + ((size_t)c0 << 7) + c8);
        uint4 q1 = *(const uint4*)(hws + ((size_t)c1 << 7) + c8);
        uint4 q2 = *(const uint4*)(hws + ((size_t)c2 << 7) + c8);
        uint4 q3 = *(const uint4*)(hws + ((size_t)c3 << 7) + c8);
        bfadd(A, q0); bfadd(B, q1); bfadd(A, q2); bfadd(B, q3);
    }
    for (; j < e; ++j) {
        int c = col[j];
        uint4 q = *(const uint4*)(hws + ((size_t)c << 7) + c8);
        bfadd(A, q);
    }
    uint4 qs = *(const uint4*)(hws + ((size_t)node << 7) + c8);
    bfadd(A, qs);
    float dv = dis[node];
    float4 bv0 = *(const float4*)(bias + c8);
    float4 bv1 = *(const float4*)(bias + c8 + 4);
    float r0 = fmaxf(dv * (A[0] + B[0]) + bv0.x, 0.f);
    float r1 = fmaxf(dv * (A[1] + B[1]) + bv0.y, 0.f);
    float r2 = fmaxf(dv * (A[2] + B[2]) + bv0.z, 0.f);
    float r3 = fmaxf(dv * (A[3] + B[3]) + bv0.w, 0.f);
    float r4 = fmaxf(dv * (A[4] + B[4]) + bv1.x, 0.f);
    float r5 = fmaxf(dv * (A[5] + B[5]) + bv1.y, 0.f);
    float r6 = fmaxf(dv * (A[6] + B[6]) + bv1.z, 0.f);
    float r7 = fmaxf(dv * (A[7] + B[7]) + bv1.w, 0.f);
    uint4 o;
    o.x = pack2(r0, r1);
    o.y = pack2(r2, r3);
    o.z = pack2(r4, r5);
    o.w = pack2(r6, r7);
    *(uint4*)(out + (size_t)node * 128 + c8) = o;
}

// ---------------- fused mean-pool + heads (bf16 h input) ----------------

__global__ __launch_bounds__(256) void k_pool_head(const ushort* __restrict__ h, const int* __restrict__ batch,
                                                   const float* __restrict__ Wmu, const float* __restrict__ bmu,
                                                   const float* __restrict__ Wlv, const float* __restrict__ blv,
                                                   float* __restrict__ out, int n) {
    int g = blockIdx.x;
    int t = threadIdx.x;
    int lo = 0, hi = n;
    while (lo < hi) { int m = (lo + hi) >> 1; if (batch[m] < g) lo = m + 1; else hi = m; }
    int start = lo;
    hi = n;
    while (lo < hi) { int m = (lo + hi) >> 1; if (batch[m] < g + 1) lo = m + 1; else hi = m; }
    int end = lo;

    __shared__ float sh0[256];
    __shared__ float sh1[256];
    __shared__ float pooled[128];
    int lane = t & 63;
    int grp = t >> 6;
    float a0 = 0.f, a1 = 0.f;
    for (int i = start + grp; i < end; i += 4) {
        uint q = *(const uint*)(h + (size_t)i * 128 + lane * 2);
        a0 += bf_lo(q);
        a1 += bf_hi(q);
    }
    sh0[t] = a0;
    sh1[t] = a1;
    __syncthreads();
    if (t < 64) {
        float cnt = (float)(end - start);
        float inv = 1.0f / fmaxf(cnt, 1.0f);
        float s0 = sh0[t] + sh0[t + 64] + sh0[t + 128] + sh0[t + 192];
        float s1 = sh1[t] + sh1[t + 64] + sh1[t + 128] + sh1[t + 192];
        pooled[t * 2] = s0 * inv;
        pooled[t * 2 + 1] = s1 * inv;
    }
    __syncthreads();
    float amu = bmu[t], alv = blv[t];
    for (int k = 0; k < 128; k += 4) {
        float p0 = pooled[k], p1 = pooled[k + 1], p2 = pooled[k + 2], p3 = pooled[k + 3];
        amu += p0 * Wmu[(k + 0) * 256 + t] + p1 * Wmu[(k + 1) * 256 + t]
             + p2 * Wmu[(k + 2) * 256 + t] + p3 * Wmu[(k + 3) * 256 + t];
        alv += p0 * Wlv[(k + 0) * 256 + t] + p1 * Wlv[(k + 1) * 256 + t]
             + p2 * Wlv[(k + 2) * 256 + t] + p3 * Wlv[(k + 3) * 256 + t];
    }
    out[(size_t)g * 256 + t] = amu;
    out[(size_t)N_GRAPHS * 256 + (size_t)g * 256 + t] = alv;
}

// ---------------- launch ----------------

extern "C" void kernel_launch(void* const* d_in, const int* in_sizes, int n_in,
                              void* d_out, int out_size, void* d_ws, size_t ws_size,
                              hipStream_t stream) {
    const float* x    = (const float*)d_in[0];
    const int*   eidx = (const int*)d_in[1];
    const int*   batch= (const int*)d_in[2];
    const float* W1   = (const float*)d_in[3];
    const float* b1   = (const float*)d_in[4];
    const float* W2   = (const float*)d_in[5];
    const float* b2   = (const float*)d_in[6];
    const float* W3   = (const float*)d_in[7];
    const float* b3   = (const float*)d_in[8];
    const float* Wmu  = (const float*)d_in[9];
    const float* bmu  = (const float*)d_in[10];
    const float* Wlv  = (const float*)d_in[11];
    const float* blv  = (const float*)d_in[12];
    float* out = (float*)d_out;

    const int N = N_NODES, E = N_EDGES;
    const int* srcp = eidx;
    const int* dstp = eidx + E;

    // workspace layout
    ushort* w1h = (ushort*)d_ws;            // 4096
    ushort* w1l = w1h + 4096;               // 4096
    ushort* w2h = w1l + 4096;               // 16384
    ushort* w2l = w2h + 16384;              // 16384
    ushort* w3h = w2l + 16384;              // 16384
    ushort* w3l = w3h + 16384;              // 16384
    ushort* A   = w3l + 16384;              // N*128 bf16 (hws, gathered)
    ushort* B   = A + (size_t)N * 128;      // N*128 bf16 (h)
    float*  dis = (float*)(B + (size_t)N * 128);  // N
    int*   rp   = (int*)(dis + N);          // N+1 (pad 2)
    int*   bktCnt   = rp + (N + 2);         // NB (pad 512)
    int*   colStart = bktCnt + 512;         // NB+1 (pad 512)
    int*   packed = colStart + 512;         // NB*CAP
    int*   col    = packed + (size_t)NB * CAP;  // E

    const int gE4096 = (E + 4095) / 4096;   // 782

    // W packs + bktCnt zeroing (one launch, runs before binA)
    k_pack_all<<<144, 256, 0, stream>>>(W1, W2, W3, w1h, w1l, w2h, w2l, w3h, w3l, bktCnt);

    // single-pass binned CSR build (col grouped by (node, src-segment))
    k_binA<<<gE4096, 512, 0, stream>>>(srcp, dstp, bktCnt, packed, E);
    k_bscan<<<1, 512, 0, stream>>>(bktCnt, colStart);
    k_binB<<<NB, 1024, 0, stream>>>(bktCnt, colStart, packed, col, rp, dis, N);

    const int gGemm = (N + 63) / 64;
    const int gAgg  = (N + 15) / 16;

    k_gemm_mfma_f32<<<gGemm, 256, 0, stream>>>(x, w1h, w1l, dis, A, N);
    k_agg<<<gAgg, 256, 0, stream>>>(A, rp, col, dis, b1, B, N);
    k_gemm_mfma_bf<<<gGemm, 256, 0, stream>>>(B, w2h, w2l, dis, A, N);
    k_agg<<<gAgg, 256, 0, stream>>>(A, rp, col, dis, b2, B, N);
    k_gemm_mfma_bf<<<gGemm, 256, 0, stream>>>(B, w3h, w3l, dis, A, N);
    k_agg<<<gAgg, 256, 0, stream>>>(A, rp, col, dis, b3, B, N);
    k_pool_head<<<N_GRAPHS, 256, 0, stream>>>(B, batch, Wmu, bmu, Wlv, blv, out, N);
}

// Round 16
// 555.752 us; speedup vs baseline: 1.0853x; 1.0322x over previous
//
#include <hip/hip_runtime.h>
#include <hip/hip_bf16.h>

#define N_NODES 100000
#define N_EDGES 3200000
#define N_GRAPHS 512
#define IN_DIM 29
#define HID 128
#define LAT 256
#define NB 391     // ceil(N_NODES/256) dst-buckets
#define CAP 9216   // per-bucket packed capacity (mean 8184, sigma~90 -> +11 sigma)

typedef unsigned int uint;
typedef unsigned short ushort;
typedef float v4f __attribute__((ext_vector_type(4)));
typedef short v8s __attribute__((ext_vector_type(8)));

// round-to-nearest-even fp32 -> bf16 (finite inputs)
__device__ __forceinline__ ushort f2bf(float f) {
    uint u = __float_as_uint(f);
    return (ushort)((u + 0x7FFFu + ((u >> 16) & 1u)) >> 16);
}
__device__ __forceinline__ float bf2f(ushort h) { return __uint_as_float(((uint)h) << 16); }
__device__ __forceinline__ float bf_lo(uint p) { return __uint_as_float(p << 16); }
__device__ __forceinline__ float bf_hi(uint p) { return __uint_as_float(p & 0xFFFF0000u); }
__device__ __forceinline__ uint pack2(float a, float b) {
    return (uint)f2bf(a) | ((uint)f2bf(b) << 16);
}

__device__ __forceinline__ void bfadd(float* a, uint4 q) {
    a[0] += bf_lo(q.x); a[1] += bf_hi(q.x);
    a[2] += bf_lo(q.y); a[3] += bf_hi(q.y);
    a[4] += bf_lo(q.z); a[5] += bf_hi(q.z);
    a[6] += bf_lo(q.w); a[7] += bf_hi(q.w);
}

// ---------------- preprocessing ----------------

// Single-pass binning: 1024 threads x 8 edges = 8192 edges/block -> per-bucket
// write runs ~21 edges (~84 B), better store combining. bin by dst>>8 into
// fixed-stride CAP regions. pack (dst&255)<<17 | src.
__global__ __launch_bounds__(1024, 2) void k_binA(const int* __restrict__ src, const int* __restrict__ dst,
                                                  int* __restrict__ bktCnt, int* __restrict__ packed, int e) {
    __shared__ int hist[NB];
    __shared__ int base[NB];
    int t = threadIdx.x;
    for (int i = t; i < NB; i += 1024) hist[i] = 0;
    __syncthreads();
    int d[8], s[8];
    const int blockStart = blockIdx.x * 8192;
    #pragma unroll
    for (int k = 0; k < 8; ++k) {
        int idx = blockStart + k * 1024 + t;
        if (idx < e) {
            d[k] = dst[idx];
            s[k] = src[idx];
            atomicAdd(&hist[d[k] >> 8], 1);
        } else d[k] = -1;
    }
    __syncthreads();
    for (int i = t; i < NB; i += 1024) {
        int c = hist[i];
        base[i] = c ? atomicAdd(&bktCnt[i], c) : 0;   // bucket-local offset
    }
    __syncthreads();
    #pragma unroll
    for (int k = 0; k < 8; ++k) {
        if (d[k] >= 0) {
            int b = d[k] >> 8;
            int pos = atomicAdd(&base[b], 1);
            if (pos < CAP) packed[b * CAP + pos] = ((d[k] & 255) << 17) | s[k];
        }
    }
}

// single block: exclusive scan of bktCnt -> colStart[NB+1] (dense col layout)
__global__ __launch_bounds__(512) void k_bscan(const int* __restrict__ bktCnt, int* __restrict__ colStart) {
    __shared__ int sh[512];
    int t = threadIdx.x;
    int v = (t < NB) ? bktCnt[t] : 0;
    if (v > CAP) v = CAP;
    sh[t] = v;
    __syncthreads();
    for (int off = 1; off < 512; off <<= 1) {
        int x = (t >= off) ? sh[t - off] : 0;
        __syncthreads();
        sh[t] += x;
        __syncthreads();
    }
    int excl = sh[t] - v;
    if (t <= NB) colStart[t] = excl;
}

// Phase B: per bucket, 1024 threads. Count per-(node, src-segment) keys
// (seg = src>>12, 25 live segments, padded 32), scan the 8192 keys -> rp & dis
// (coalesced) + per-key cursors, then scatter col grouped by (node, seg) with
// seg ascending (1 MB segments) for k_agg gather locality. packed read twice
// (L2-warm) instead of LDS staging to fit the 32 KB cnt array.
__global__ __launch_bounds__(1024, 2) void k_binB(const int* __restrict__ bktCnt, const int* __restrict__ colStart,
                                                  const int* __restrict__ packed, int* __restrict__ col,
                                                  int* __restrict__ rp, float* __restrict__ dis, int n) {
    __shared__ int cnt[8192];     // 32 KB: per-(node,seg) counts -> cursors
    __shared__ int sh[1024];      // 4 KB: block scan of 1024 partial sums
    const int b = blockIdx.x;
    int cntB = bktCnt[b];
    if (cntB > CAP) cntB = CAP;
    const int segS = b * CAP;
    const int colBase = colStart[b];
    int t = threadIdx.x;
    #pragma unroll
    for (int k = 0; k < 8; ++k) cnt[t + k * 1024] = 0;
    __syncthreads();
    for (int j = t; j < cntB; j += 1024) {
        int pk = packed[segS + j];
        int key = ((pk >> 17) << 5) | ((pk & 0x1FFFF) >> 12);
        atomicAdd(&cnt[key], 1);
    }
    __syncthreads();
    // exclusive scan of cnt[8192]: thread t owns keys [8t, 8t+8)
    int base8 = t << 3;
    int v[8];
    int sum = 0;
    #pragma unroll
    for (int k = 0; k < 8; ++k) { v[k] = cnt[base8 + k]; sum += v[k]; }
    sh[t] = sum;
    __syncthreads();
    for (int off = 1; off < 1024; off <<= 1) {
        int x = (t >= off) ? sh[t - off] : 0;
        __syncthreads();
        sh[t] += x;
        __syncthreads();
    }
    int run = colBase + sh[t] - sum;
    #pragma unroll
    for (int k = 0; k < 8; ++k) { cnt[base8 + k] = run; run += v[k]; }
    __syncthreads();
    if (t < 256) {
        int node = (b << 8) + t;
        int start = cnt[t << 5];
        int next = (t == 255) ? (colBase + cntB) : cnt[(t + 1) << 5];
        int deg = next - start;
        if (node <= n) rp[node] = start;      // node==n (last bucket) -> rp[n] = E
        if (node < n) dis[node] = rsqrtf((float)deg + 1.0f);
    }
    __syncthreads();
    for (int j = t; j < cntB; j += 1024) {
        int pk = packed[segS + j];
        int key = ((pk >> 17) << 5) | ((pk & 0x1FFFF) >> 12);
        int pos = atomicAdd(&cnt[key], 1);
        col[pos] = pk & 0x1FFFF;
    }
}

// ---------------- W pack (all 3 layers) + zero bktCnt (runs first) ----------------
// layout index = ((kstep*8 + ntile)*64 + lane)*8 + j
// element = W[kstep*32 + (lane>>4)*8 + j][ntile*16 + (lane&15)]

__device__ __forceinline__ void pack_one(const float* W, ushort* hi, ushort* lo, int Ksrc, int idx) {
    int j = idx & 7;
    int lane = (idx >> 3) & 63;
    int nt = (idx >> 9) & 7;
    int ks = idx >> 12;
    int k = ks * 32 + (lane >> 4) * 8 + j;
    int n = nt * 16 + (lane & 15);
    float v = (k < Ksrc) ? W[k * 128 + n] : 0.f;
    ushort h = f2bf(v);
    ushort l = f2bf(v - bf2f(h));
    hi[idx] = h;
    lo[idx] = l;
}

__global__ __launch_bounds__(256) void k_pack_all(const float* __restrict__ W1, const float* __restrict__ W2,
                                                  const float* __restrict__ W3,
                                                  ushort* w1h, ushort* w1l, ushort* w2h, ushort* w2l,
                                                  ushort* w3h, ushort* w3l, int* __restrict__ bktCnt) {
    int idx = blockIdx.x * 256 + threadIdx.x;
    if (idx < NB) bktCnt[idx] = 0;        // fold the zeroing launch in here
    if (idx < 4096) {
        pack_one(W1, w1h, w1l, IN_DIM, idx);
    } else if (idx < 4096 + 16384) {
        pack_one(W2, w2h, w2l, HID, idx - 4096);
    } else if (idx < 4096 + 32768) {
        pack_one(W3, w3h, w3l, HID, idx - 4096 - 16384);
    }
}

// ---------------- MFMA GEMM (layer 1): hws = dis * (x_f32 @ W) ----------------
// Split precision: acc = Ahi@Whi + Ahi@Wlo + Alo@Whi.

__global__ __launch_bounds__(256, 6) void k_gemm_mfma_f32(const float* __restrict__ in,
                                                          const ushort* __restrict__ Whi,
                                                          const ushort* __restrict__ Wlo,
                                                          const float* __restrict__ dis,
                                                          ushort* __restrict__ out, int n) {
    const int wave = threadIdx.x >> 6;
    const int lane = threadIdx.x & 63;
    const int m0 = (blockIdx.x * 4 + wave) * 16;
    if (m0 >= n) return;
    int row = m0 + (lane & 15);
    if (row >= n) row = n - 1;
    const int kh = (lane >> 4) * 8;
    const float* rptr = in + (size_t)row * IN_DIM + kh;

    v4f acc[8];
    #pragma unroll
    for (int t = 0; t < 8; ++t) acc[t] = (v4f){0.f, 0.f, 0.f, 0.f};

    float a[8];
    #pragma unroll
    for (int j = 0; j < 8; ++j) a[j] = (kh + j < IN_DIM) ? rptr[j] : 0.f;
    v8s ahi, alo;
    #pragma unroll
    for (int j = 0; j < 8; ++j) {
        ushort h = f2bf(a[j]);
        ushort l = f2bf(a[j] - bf2f(h));
        ahi[j] = (short)h;
        alo[j] = (short)l;
    }
    const ushort* bh = Whi + (size_t)lane * 8;
    const ushort* bl = Wlo + (size_t)lane * 8;
    #pragma unroll
    for (int nt = 0; nt < 8; ++nt) {
        v8s bhi = *(const v8s*)(bh + nt * 512);
        v8s blo = *(const v8s*)(bl + nt * 512);
        acc[nt] = __builtin_amdgcn_mfma_f32_16x16x32_bf16(ahi, bhi, acc[nt], 0, 0, 0);
        acc[nt] = __builtin_amdgcn_mfma_f32_16x16x32_bf16(ahi, blo, acc[nt], 0, 0, 0);
        acc[nt] = __builtin_amdgcn_mfma_f32_16x16x32_bf16(alo, bhi, acc[nt], 0, 0, 0);
    }

    const int orow0 = m0 + (lane >> 4) * 4;
    const int col0 = lane & 15;
    #pragma unroll
    for (int r = 0; r < 4; ++r) {
        int orow = orow0 + r;
        if (orow < n) {
            float dv = dis[orow];
            #pragma unroll
            for (int nt = 0; nt < 8; ++nt)
                out[(size_t)orow * 128 + nt * 16 + col0] = f2bf(acc[nt][r] * dv);
        }
    }
}

// ---------------- MFMA GEMM (layers 2,3): hws = dis * (h_bf16 @ W) ----------------
// A exact bf16 -> 2 MFMAs: A@Whi + A@Wlo.

__global__ __launch_bounds__(256, 6) void k_gemm_mfma_bf(const ushort* __restrict__ in,
                                                         const ushort* __restrict__ Whi,
                                                         const ushort* __restrict__ Wlo,
                                                         const float* __restrict__ dis,
                                                         ushort* __restrict__ out, int n) {
    const int wave = threadIdx.x >> 6;
    const int lane = threadIdx.x & 63;
    const int m0 = (blockIdx.x * 4 + wave) * 16;
    if (m0 >= n) return;
    int row = m0 + (lane & 15);
    if (row >= n) row = n - 1;
    const int kh = (lane >> 4) * 8;
    const ushort* rptr = in + (size_t)row * 128 + kh;

    v4f acc[8];
    #pragma unroll
    for (int t = 0; t < 8; ++t) acc[t] = (v4f){0.f, 0.f, 0.f, 0.f};

    #pragma unroll
    for (int ks = 0; ks < 4; ++ks) {
        v8s a = *(const v8s*)(rptr + ks * 32);
        const ushort* bh = Whi + (size_t)(ks * 8) * 512 + (size_t)lane * 8;
        const ushort* bl = Wlo + (size_t)(ks * 8) * 512 + (size_t)lane * 8;
        #pragma unroll
        for (int nt = 0; nt < 8; ++nt) {
            v8s bhi = *(const v8s*)(bh + nt * 512);
            v8s blo = *(const v8s*)(bl + nt * 512);
            acc[nt] = __builtin_amdgcn_mfma_f32_16x16x32_bf16(a, bhi, acc[nt], 0, 0, 0);
            acc[nt] = __builtin_amdgcn_mfma_f32_16x16x32_bf16(a, blo, acc[nt], 0, 0, 0);
        }
    }

    const int orow0 = m0 + (lane >> 4) * 4;
    const int col0 = lane & 15;
    #pragma unroll
    for (int r = 0; r < 4; ++r) {
        int orow = orow0 + r;
        if (orow < n) {
            float dv = dis[orow];
            #pragma unroll
            for (int nt = 0; nt < 8; ++nt)
                out[(size_t)orow * 128 + nt * 16 + col0] = f2bf(acc[nt][r] * dv);
        }
    }
}

// ---------------- aggregation (R9/R14-exact): 16 lanes/node, 8 ch/lane, 4 edges in flight ----------------
// out[i][:] = bf16( relu( dis[i] * ( sum_j hws[col[j]][:] + hws[i][:] ) + b[:] ) )

__global__ __launch_bounds__(256, 8) void k_agg(const ushort* __restrict__ hws, const int* __restrict__ rp,
                                                const int* __restrict__ col, const float* __restrict__ dis,
                                                const float* __restrict__ bias, ushort* __restrict__ out, int n) {
    int node = (int)((blockIdx.x * 256 + threadIdx.x) >> 4);
    if (node >= n) return;
    int c8 = (threadIdx.x & 15) << 3;
    int s = rp[node], e = rp[node + 1];
    float A[8] = {0.f, 0.f, 0.f, 0.f, 0.f, 0.f, 0.f, 0.f};
    float B[8] = {0.f, 0.f, 0.f, 0.f, 0.f, 0.f, 0.f, 0.f};
    int j = s;
    for (; j + 3 < e; j += 4) {
        int c0 = col[j], c1 = col[j + 1], c2 = col[j + 2], c3 = col[j + 3];
        uint4 q0 = *(const uint4*)(hws + ((size_t)c0 << 7) + c8);
        uint4 q1 = *(const uint4*)(hws + ((size_t)c1 << 7) + c8);
        uint4 q2 = *(const uint4*)(hws + ((size_t)c2 << 7) + c8);
        uint4 q3 = *(const uint4*)(hws + ((size_t)c3 << 7) + c8);
        bfadd(A, q0); bfadd(B, q1); bfadd(A, q2); bfadd(B, q3);
    }
    for (; j < e; ++j) {
        int c = col[j];
        uint4 q = *(const uint4*)(hws + ((size_t)c << 7) + c8);
        bfadd(A, q);
    }
    uint4 qs = *(const uint4*)(hws + ((size_t)node << 7) + c8);
    bfadd(A, qs);
    float dv = dis[node];
    float4 bv0 = *(const float4*)(bias + c8);
    float4 bv1 = *(const float4*)(bias + c8 + 4);
    float r0 = fmaxf(dv * (A[0] + B[0]) + bv0.x, 0.f);
    float r1 = fmaxf(dv * (A[1] + B[1]) + bv0.y, 0.f);
    float r2 = fmaxf(dv * (A[2] + B[2]) + bv0.z, 0.f);
    float r3 = fmaxf(dv * (A[3] + B[3]) + bv0.w, 0.f);
    float r4 = fmaxf(dv * (A[4] + B[4]) + bv1.x, 0.f);
    float r5 = fmaxf(dv * (A[5] + B[5]) + bv1.y, 0.f);
    float r6 = fmaxf(dv * (A[6] + B[6]) + bv1.z, 0.f);
    float r7 = fmaxf(dv * (A[7] + B[7]) + bv1.w, 0.f);
    uint4 o;
    o.x = pack2(r0, r1);
    o.y = pack2(r2, r3);
    o.z = pack2(r4, r5);
    o.w = pack2(r6, r7);
    *(uint4*)(out + (size_t)node * 128 + c8) = o;
}

// ---------------- fused mean-pool + heads (bf16 h input) ----------------

__global__ __launch_bounds__(256) void k_pool_head(const ushort* __restrict__ h, const int* __restrict__ batch,
                                                   const float* __restrict__ Wmu, const float* __restrict__ bmu,
                                                   const float* __restrict__ Wlv, const float* __restrict__ blv,
                                                   float* __restrict__ out, int n) {
    int g = blockIdx.x;
    int t = threadIdx.x;
    int lo = 0, hi = n;
    while (lo < hi) { int m = (lo + hi) >> 1; if (batch[m] < g) lo = m + 1; else hi = m; }
    int start = lo;
    hi = n;
    while (lo < hi) { int m = (lo + hi) >> 1; if (batch[m] < g + 1) lo = m + 1; else hi = m; }
    int end = lo;

    __shared__ float sh0[256];
    __shared__ float sh1[256];
    __shared__ float pooled[128];
    int lane = t & 63;
    int grp = t >> 6;
    float a0 = 0.f, a1 = 0.f;
    for (int i = start + grp; i < end; i += 4) {
        uint q = *(const uint*)(h + (size_t)i * 128 + lane * 2);
        a0 += bf_lo(q);
        a1 += bf_hi(q);
    }
    sh0[t] = a0;
    sh1[t] = a1;
    __syncthreads();
    if (t < 64) {
        float cnt = (float)(end - start);
        float inv = 1.0f / fmaxf(cnt, 1.0f);
        float s0 = sh0[t] + sh0[t + 64] + sh0[t + 128] + sh0[t + 192];
        float s1 = sh1[t] + sh1[t + 64] + sh1[t + 128] + sh1[t + 192];
        pooled[t * 2] = s0 * inv;
        pooled[t * 2 + 1] = s1 * inv;
    }
    __syncthreads();
    float amu = bmu[t], alv = blv[t];
    for (int k = 0; k < 128; k += 4) {
        float p0 = pooled[k], p1 = pooled[k + 1], p2 = pooled[k + 2], p3 = pooled[k + 3];
        amu += p0 * Wmu[(k + 0) * 256 + t] + p1 * Wmu[(k + 1) * 256 + t]
             + p2 * Wmu[(k + 2) * 256 + t] + p3 * Wmu[(k + 3) * 256 + t];
        alv += p0 * Wlv[(k + 0) * 256 + t] + p1 * Wlv[(k + 1) * 256 + t]
             + p2 * Wlv[(k + 2) * 256 + t] + p3 * Wlv[(k + 3) * 256 + t];
    }
    out[(size_t)g * 256 + t] = amu;
    out[(size_t)N_GRAPHS * 256 + (size_t)g * 256 + t] = alv;
}

// ---------------- launch ----------------

extern "C" void kernel_launch(void* const* d_in, const int* in_sizes, int n_in,
                              void* d_out, int out_size, void* d_ws, size_t ws_size,
                              hipStream_t stream) {
    const float* x    = (const float*)d_in[0];
    const int*   eidx = (const int*)d_in[1];
    const int*   batch= (const int*)d_in[2];
    const float* W1   = (const float*)d_in[3];
    const float* b1   = (const float*)d_in[4];
    const float* W2   = (const float*)d_in[5];
    const float* b2   = (const float*)d_in[6];
    const float* W3   = (const float*)d_in[7];
    const float* b3   = (const float*)d_in[8];
    const float* Wmu  = (const float*)d_in[9];
    const float* bmu  = (const float*)d_in[10];
    const float* Wlv  = (const float*)d_in[11];
    const float* blv  = (const float*)d_in[12];
    float* out = (float*)d_out;

    const int N = N_NODES, E = N_EDGES;
    const int* srcp = eidx;
    const int* dstp = eidx + E;

    // workspace layout
    ushort* w1h = (ushort*)d_ws;            // 4096
    ushort* w1l = w1h + 4096;               // 4096
    ushort* w2h = w1l + 4096;               // 16384
    ushort* w2l = w2h + 16384;              // 16384
    ushort* w3h = w2l + 16384;              // 16384
    ushort* w3l = w3h + 16384;              // 16384
    ushort* A   = w3l + 16384;              // N*128 bf16 (hws, gathered)
    ushort* B   = A + (size_t)N * 128;      // N*128 bf16 (h)
    float*  dis = (float*)(B + (size_t)N * 128);  // N
    int*   rp   = (int*)(dis + N);          // N+1 (pad 2)
    int*   bktCnt   = rp + (N + 2);         // NB (pad 512)
    int*   colStart = bktCnt + 512;         // NB+1 (pad 512)
    int*   packed = colStart + 512;         // NB*CAP
    int*   col    = packed + (size_t)NB * CAP;  // E

    const int gE8192 = (E + 8191) / 8192;   // 391

    // W packs + bktCnt zeroing (one launch, runs before binA)
    k_pack_all<<<144, 256, 0, stream>>>(W1, W2, W3, w1h, w1l, w2h, w2l, w3h, w3l, bktCnt);

    // single-pass binned CSR build (col grouped by (node, 1MB src-segment))
    k_binA<<<gE8192, 1024, 0, stream>>>(srcp, dstp, bktCnt, packed, E);
    k_bscan<<<1, 512, 0, stream>>>(bktCnt, colStart);
    k_binB<<<NB, 1024, 0, stream>>>(bktCnt, colStart, packed, col, rp, dis, N);

    const int gGemm = (N + 63) / 64;
    const int gAgg  = (N + 15) / 16;

    k_gemm_mfma_f32<<<gGemm, 256, 0, stream>>>(x, w1h, w1l, dis, A, N);
    k_agg<<<gAgg, 256, 0, stream>>>(A, rp, col, dis, b1, B, N);
    k_gemm_mfma_bf<<<gGemm, 256, 0, stream>>>(B, w2h, w2l, dis, A, N);
    k_agg<<<gAgg, 256, 0, stream>>>(A, rp, col, dis, b2, B, N);
    k_gemm_mfma_bf<<<gGemm, 256, 0, stream>>>(B, w3h, w3l, dis, A, N);
    k_agg<<<gAgg, 256, 0, stream>>>(A, rp, col, dis, b3, B, N);
    k_pool_head<<<N_GRAPHS, 256, 0, stream>>>(B, batch, Wmu, bmu, Wlv, blv, out, N);
}